// Round 7
// baseline (200.541 us; speedup 1.0000x reference)
//
#include <hip/hip_runtime.h>
#include <math.h>

#define EPSF 1e-6f
#define NB    1024
#define ND    512
#define NCAND 40000
#define NPAD  40064          // 313 * 128
#define NCHUNK 626           // NPAD / 64 : one partial per (row, 64-col chunk)
#define LOG2E 1.44269504088896340736f

typedef __attribute__((ext_vector_type(8))) short          bf16x8;
typedef __attribute__((ext_vector_type(8))) unsigned short ushort8;
typedef __attribute__((ext_vector_type(4))) float          f32x4;

// ---------- helpers ----------
__device__ __forceinline__ unsigned short f2bf(float f) {
  union { float f; unsigned int u; } v; v.f = f;
  unsigned int u = v.u;
  return (unsigned short)((u + 0x7FFFu + ((u >> 16) & 1u)) >> 16);  // RNE
}

__device__ __forceinline__ void gload_lds16(const void* g, void* l) {
  __builtin_amdgcn_global_load_lds(
      (const __attribute__((address_space(1))) void*)g,
      (__attribute__((address_space(3))) void*)l, 16, 0, 0);
}

// ---------- fused prep: one kernel does everything pre-GEMM ----------
__global__ __launch_bounds__(256) void prep_all_kernel(
    const float* __restrict__ q, const float* __restrict__ cand,
    const float* __restrict__ bias, const float* __restrict__ curv,
    const int* __restrict__ target,
    unsigned short* __restrict__ qb, unsigned short* __restrict__ cb,
    float* __restrict__ ysq, float4* __restrict__ rcst,
    float* __restrict__ b2, float* __restrict__ tgtl)
{
  const int blk = blockIdx.x;
  const int tid = threadIdx.x, wid = tid >> 6, lane = tid & 63;

  // ---- candidate rows (all blocks) ----
  {
    const long row = (long)blk * 4 + wid;          // < NPAD by grid size
    float vals[8];
    if (row < NCAND) {
      const float4* s = (const float4*)(cand + row * ND + lane * 8);
      float4 a = s[0], b = s[1];
      vals[0]=a.x; vals[1]=a.y; vals[2]=a.z; vals[3]=a.w;
      vals[4]=b.x; vals[5]=b.y; vals[6]=b.z; vals[7]=b.w;
    } else {
      #pragma unroll
      for (int i = 0; i < 8; ++i) vals[i] = 0.f;
    }
    float ss = 0.f; ushort8 o;
    #pragma unroll
    for (int i = 0; i < 8; ++i) { ss = fmaf(vals[i], vals[i], ss); o[i] = f2bf(vals[i]); }
    *(ushort8*)(cb + row * ND + lane * 8) = o;
    #pragma unroll
    for (int m = 1; m < 64; m <<= 1) ss += __shfl_xor(ss, m, 64);
    if (lane == 0) ysq[row] = ss;
  }

  if (blk >= 256) return;

  // ---- b2 fill ----
  {
    const int g = blk * 256 + tid;
    if (g < NPAD) b2[g] = (g < NCAND) ? bias[g] * LOG2E : -INFINITY;
  }

  // ---- query rows ----
  {
    const long row = (long)blk * 4 + wid;          // < 1024
    const float4* s = (const float4*)(q + row * ND + lane * 8);
    float4 a = s[0], b = s[1];
    float vals[8] = {a.x,a.y,a.z,a.w,b.x,b.y,b.z,b.w};
    float ss = 0.f; ushort8 o;
    #pragma unroll
    for (int i = 0; i < 8; ++i) { ss = fmaf(vals[i], vals[i], ss); o[i] = f2bf(vals[i]); }
    *(ushort8*)(qb + row * ND + lane * 8) = o;
    #pragma unroll
    for (int m = 1; m < 64; m <<= 1) ss += __shfl_xor(ss, m, 64);
    if (lane == 0) {
      const float c   = curv[row];
      const float scv = sqrtf(c + EPSF);
      const float inv = 1.f / (scv + EPSF);
      rcst[row] = make_float4(-c, fmaf(-c, ss, 1.f), inv, 2.f * c * c * ss);
    }
  }

  // ---- exact fp32 target logit (wave per row) ----
  {
    const int b = blk * 4 + wid;                   // < 1024
    const int t = target[b];
    const float4* qp = (const float4*)(q + (long)b * ND + lane * 8);
    const float4* cp = (const float4*)(cand + (long)t * ND + lane * 8);
    float4 a0 = qp[0], a1 = qp[1], c0 = cp[0], c1 = cp[1];
    float qa[8] = {a0.x,a0.y,a0.z,a0.w,a1.x,a1.y,a1.z,a1.w};
    float ca[8] = {c0.x,c0.y,c0.z,c0.w,c1.x,c1.y,c1.z,c1.w};
    float xy = 0.f, xs = 0.f, ys = 0.f;
    #pragma unroll
    for (int i = 0; i < 8; ++i) {
      xy = fmaf(qa[i], ca[i], xy);
      xs = fmaf(qa[i], qa[i], xs);
      ys = fmaf(ca[i], ca[i], ys);
    }
    #pragma unroll
    for (int m = 1; m < 64; m <<= 1) {
      xy += __shfl_xor(xy, m, 64);
      xs += __shfl_xor(xs, m, 64);
      ys += __shfl_xor(ys, m, 64);
    }
    if (lane == 0) {
      float c  = curv[b];
      float sc = sqrtf(c + EPSF);
      float A  = 1.f - 2.f * c * xy + c * ys;
      float Bc = 1.f - c * xs;
      float nsq = A * A * xs - 2.f * A * Bc * xy + Bc * Bc * ys;
      float den = 1.f - 2.f * c * xy + c * c * xs * ys;
      float dn  = sqrtf(fmaxf(nsq, 0.f)) / (den + EPSF);
      dn = fminf(fmaxf(dn, EPSF), 1.f / (sc + EPSF) - EPSF);
      float tt  = fminf(sc * dn, 1.f - EPSF);
      float dist = 2.f / (sc + EPSF) * atanhf(tt);
      tgtl[b] = bias[t] - dist;
    }
  }
}

// ---------- fused bf16 GEMM + acosh epilogue + partial expsum ----------
// 128x128 tile, BK=32 DOUBLE-BUFFERED (T3 minimum-2-phase: stage t+1 issued
// before compute of t; one vmcnt-draining barrier per K-step). LDS still
// 32 KB -> 4 blocks/CU. 64-byte rows, XOR slot swizzle s = l4 ^ (row&3)
// (both-sides involution, rule #21). T5 setprio around each MFMA cluster.
__global__ __launch_bounds__(256, 4) void gemm_epi_kernel(
    const unsigned short* __restrict__ Qb,   // [NB][ND] bf16
    const unsigned short* __restrict__ Cb,   // [NPAD][ND] bf16
    const float4* __restrict__ rcst,         // [NB] (negc, Bc, inv, 2c^2xs)
    const float* __restrict__ ysq,           // [NPAD]
    const float* __restrict__ b2,            // [NPAD] bias*log2e, pad=-inf
    float* __restrict__ partials)            // [NB][NCHUNK]
{
  __shared__ unsigned short As[2][128 * 32];
  __shared__ unsigned short Bs[2][128 * 32];
  const int tid  = threadIdx.x;
  const int lane = tid & 63;
  const int wid  = tid >> 6;
  const int wr   = wid >> 1, wc = wid & 1;
  const int l15  = lane & 15, l4 = lane >> 4;

  // XCD-aware remap (T1)
  const int h  = blockIdx.x;            // 2504 = 8*313
  const int w  = (h & 7) * 313 + (h >> 3);
  const int bm = w & 7, bn = w >> 3;

  f32x4 acc[4][4] = {};

  const unsigned short* qbase = Qb + (long)bm * 128 * ND;
  const unsigned short* cbase = Cb + (long)bn * 128 * ND;

  // ---- staging geometry: e in [0,512), r = e>>2, slot = e&3,
  //      source chunk = slot ^ (r&3), LDS dest linear at e*16 bytes ----
  const int e0 = tid, e1 = 256 + tid;
  const int r0 = e0 >> 2, r1 = e1 >> 2;
  const int g0 = ((e0 & 3) ^ (r0 & 3)) * 8;
  const int g1 = ((e1 & 3) ^ (r1 & 3)) * 8;
  const unsigned short* qs0 = qbase + (long)r0 * ND + g0;
  const unsigned short* qs1 = qbase + (long)r1 * ND + g1;
  const unsigned short* cs0 = cbase + (long)r0 * ND + g0;
  const unsigned short* cs1 = cbase + (long)r1 * ND + g1;
  const int d0 = e0 * 8, d1 = e1 * 8;   // ushort index into tile

  // ---- read geometry: byte = row*64 + ((l4*16) ^ ((row&3)<<4));
  //      row&3 == l15&3 since wr*64, i*16 are multiples of 4 ----
  int aoff[4], boff[4];
  #pragma unroll
  for (int i = 0; i < 4; ++i) {
    const int ra = wr * 64 + i * 16 + l15;
    const int rb = wc * 64 + i * 16 + l15;
    const int sw = (l4 * 16) ^ ((l15 & 3) << 4);
    aoff[i] = ra * 64 + sw;
    boff[i] = rb * 64 + sw;
  }

#define STAGE(B, KOF) do { \
    gload_lds16(qs0 + (KOF), &As[B][d0]); \
    gload_lds16(qs1 + (KOF), &As[B][d1]); \
    gload_lds16(cs0 + (KOF), &Bs[B][d0]); \
    gload_lds16(cs1 + (KOF), &Bs[B][d1]); \
  } while (0)

#define COMPUTE(B) do { \
    bf16x8 a[4], b[4]; \
    _Pragma("unroll") \
    for (int i = 0; i < 4; ++i) a[i] = *(const bf16x8*)((const char*)As[B] + aoff[i]); \
    _Pragma("unroll") \
    for (int j = 0; j < 4; ++j) b[j] = *(const bf16x8*)((const char*)Bs[B] + boff[j]); \
    __builtin_amdgcn_s_setprio(1); \
    _Pragma("unroll") \
    for (int i = 0; i < 4; ++i) \
      _Pragma("unroll") \
      for (int j = 0; j < 4; ++j) \
        acc[i][j] = __builtin_amdgcn_mfma_f32_16x16x32_bf16(a[i], b[j], acc[i][j], 0, 0, 0); \
    __builtin_amdgcn_s_setprio(0); \
  } while (0)

  STAGE(0, 0);
  __syncthreads();                       // buf0 ready (vmcnt drained)
  #pragma unroll 1
  for (int t = 0; t < 16; t += 2) {
    STAGE(1, (t + 1) * 32);              // t+1 <= 15 always
    COMPUTE(0);                          // overlaps buf1 staging
    __syncthreads();                     // buf1 ready; buf0 reads done
    if (t < 14) STAGE(0, (t + 2) * 32);
    COMPUTE(1);
    __syncthreads();
  }
#undef STAGE
#undef COMPUTE

  // ---- epilogue (acosh form) ----
  const int rbase = bm * 128 + wr * 64;
  const int cb0   = bn * 128 + wc * 64 + l15;
  float ysv[4], bv[4];
  #pragma unroll
  for (int j = 0; j < 4; ++j) { ysv[j] = ysq[cb0 + j * 16]; bv[j] = b2[cb0 + j * 16]; }

  #pragma unroll
  for (int i = 0; i < 4; ++i) {
    #pragma unroll
    for (int r = 0; r < 4; ++r) {
      const int grow = rbase + i * 16 + l4 * 4 + r;
      const float4 rc = rcst[grow];
      const float negc = rc.x, Bc = rc.y, inv = rc.z, c2xs2 = rc.w;
      const float n4c = 4.f * negc;               // -4c
      float s = 0.f;
      #pragma unroll
      for (int j = 0; j < 4; ++j) {
        const float xy   = acc[i][j][r];
        const float By   = fmaf(negc, ysv[j], 1.f);
        const float P    = Bc * By;
        const float den2 = fmaf(c2xs2, ysv[j], fmaf(n4c, xy, 2.f));   // 2*den
        const float wv   = fmaf(den2, __builtin_amdgcn_rcpf(P), -1.f);
        const float t2   = fmaxf(fmaf(wv, wv, -1.f), 0.f);
        const float W    = wv + __builtin_amdgcn_sqrtf(t2);
        const float lg   = __builtin_amdgcn_logf(W);                  // log2
        s += __builtin_amdgcn_exp2f(fmaf(-inv, lg, bv[j]));
      }
      s += __shfl_xor(s, 1, 64);
      s += __shfl_xor(s, 2, 64);
      s += __shfl_xor(s, 4, 64);
      s += __shfl_xor(s, 8, 64);
      if (l15 == 0) partials[(long)grow * NCHUNK + (bn * 2 + wc)] = s;
    }
  }
}

// ---------- per-row LSE (no atomics) ----------
__global__ __launch_bounds__(128) void lse_row_kernel(
    const float* __restrict__ partials, const float* __restrict__ tgtl,
    float* __restrict__ rowloss)
{
  const int b = blockIdx.x;
  const int tid = threadIdx.x;
  float s = 0.f;
  for (int i = tid; i < NCHUNK; i += 128) s += partials[(long)b * NCHUNK + i];
  #pragma unroll
  for (int m = 1; m < 64; m <<= 1) s += __shfl_xor(s, m, 64);
  __shared__ float red[2];
  if ((tid & 63) == 0) red[tid >> 6] = s;
  __syncthreads();
  if (tid == 0) rowloss[b] = logf(red[0] + red[1]) - tgtl[b];
}

// ---------- deterministic final mean: one block, no atomics ----------
__global__ __launch_bounds__(256) void final_sum_kernel(
    const float* __restrict__ rowloss, float* __restrict__ out)
{
  const int tid = threadIdx.x;
  float s = rowloss[tid] + rowloss[tid + 256] + rowloss[tid + 512] + rowloss[tid + 768];
  #pragma unroll
  for (int m = 1; m < 64; m <<= 1) s += __shfl_xor(s, m, 64);
  __shared__ float red[4];
  if ((tid & 63) == 0) red[tid >> 6] = s;
  __syncthreads();
  if (tid == 0) out[0] = (red[0] + red[1] + red[2] + red[3]) * (1.0f / (float)NB);
}

// ---------- launch ----------
extern "C" void kernel_launch(void* const* d_in, const int* in_sizes, int n_in,
                              void* d_out, int out_size, void* d_ws, size_t ws_size,
                              hipStream_t stream) {
  const float* q    = (const float*)d_in[0];
  const float* cand = (const float*)d_in[1];
  const float* bias = (const float*)d_in[2];
  const float* curv = (const float*)d_in[3];
  const int*   tgt  = (const int*)d_in[4];
  float* out = (float*)d_out;

  char* ws = (char*)d_ws;
  unsigned short* cb = (unsigned short*)(ws);                 // 41,025,536
  unsigned short* qb = (unsigned short*)(ws + 41025536);      //  1,048,576
  float*  ysq        = (float*) (ws + 42074112);              //    160,256
  float*  b2         = (float*) (ws + 42234368);              //    160,256
  float4* rcst       = (float4*)(ws + 42394624);              //     16,384
  float*  tgtl       = (float*) (ws + 42411008);              //      4,096
  float*  rowloss    = (float*) (ws + 42415104);              //      4,096
  float*  partials   = (float*) (ws + 42419200);              //  2,564,096 -> end 44,983,296

  prep_all_kernel<<<NPAD / 4, 256, 0, stream>>>(q, cand, bias, curv, tgt,
                                                qb, cb, ysq, rcst, b2, tgtl);
  gemm_epi_kernel<<<2504, 256, 0, stream>>>(qb, cb, rcst, ysq, b2, partials);
  lse_row_kernel<<<NB, 128, 0, stream>>>(partials, tgtl, rowloss);
  final_sum_kernel<<<1, 256, 0, stream>>>(rowloss, out);
}